// Round 1
// baseline (2462.898 us; speedup 1.0000x reference)
//
#include <hip/hip_runtime.h>
#include <hip/hip_bf16.h>

typedef __attribute__((ext_vector_type(8))) short short8;
typedef __attribute__((ext_vector_type(4))) float f32x4;

#define EMB   1024
#define DFF   4096
#define S_LEN 2048
#define NB    2
#define MTOT  (NB * S_LEN)   // 4096
#define HEADS 16
#define HDIM  64

__device__ __forceinline__ float bf2f(unsigned short u) {
  return __uint_as_float(((unsigned int)u) << 16);
}
__device__ __forceinline__ unsigned short f2bf(float f) {
  unsigned int x = __float_as_uint(f);
  unsigned int r = (x + 0x7fffu + ((x >> 16) & 1u)) >> 16;  // RN, no NaN inputs here
  return (unsigned short)r;
}

// ---------------------------------------------------------------------------
// Weight fp32 [K,N] -> bf16 [N,K]  (so GEMM reads both operands K-contiguous)
// block (32,8), grid (N/32, K/32)
// ---------------------------------------------------------------------------
__global__ __launch_bounds__(256) void transpose_to_bf16(
    const float* __restrict__ W, unsigned short* __restrict__ Wt, int K, int N)
{
  __shared__ float t[32][33];
  const int n0 = blockIdx.x * 32, k0 = blockIdx.y * 32;
  const int tx = threadIdx.x, ty = threadIdx.y;
#pragma unroll
  for (int i = 0; i < 4; ++i) {
    int r = ty + i * 8;
    t[r][tx] = W[(size_t)(k0 + r) * N + n0 + tx];
  }
  __syncthreads();
#pragma unroll
  for (int i = 0; i < 4; ++i) {
    int r = ty + i * 8;
    Wt[(size_t)(n0 + r) * K + k0 + tx] = f2bf(t[tx][r]);
  }
}

// ---------------------------------------------------------------------------
// LayerNorm: fp32 [rows,1024] -> bf16 [rows,1024].  block 256, grid rows.
// ---------------------------------------------------------------------------
__global__ __launch_bounds__(256) void ln_kernel(
    const float* __restrict__ X, const float* __restrict__ g,
    const float* __restrict__ sh, unsigned short* __restrict__ H)
{
  const int row = blockIdx.x, t = threadIdx.x;
  const float* xr = X + (size_t)row * EMB;
  float4 v = *(const float4*)(xr + t * 4);
  float s  = v.x + v.y + v.z + v.w;
  float ss = v.x * v.x + v.y * v.y + v.z * v.z + v.w * v.w;
#pragma unroll
  for (int off = 32; off > 0; off >>= 1) {
    s  += __shfl_xor(s, off);
    ss += __shfl_xor(ss, off);
  }
  __shared__ float rs[4], rss[4];
  const int wid = t >> 6;
  if ((t & 63) == 0) { rs[wid] = s; rss[wid] = ss; }
  __syncthreads();
  s  = rs[0] + rs[1] + rs[2] + rs[3];
  ss = rss[0] + rss[1] + rss[2] + rss[3];
  const float mean = s * (1.f / EMB);
  const float var  = ss * (1.f / EMB) - mean * mean;
  const float rstd = rsqrtf(var + 1e-5f);
  float4 gv = *(const float4*)(g + t * 4);
  float4 sv = *(const float4*)(sh + t * 4);
  ushort4 o;
  o.x = f2bf((v.x - mean) * rstd * gv.x + sv.x);
  o.y = f2bf((v.y - mean) * rstd * gv.y + sv.y);
  o.z = f2bf((v.z - mean) * rstd * gv.z + sv.z);
  o.w = f2bf((v.w - mean) * rstd * gv.w + sv.w);
  *(ushort4*)(H + (size_t)row * EMB + t * 4) = o;
}

// ---------------------------------------------------------------------------
// GEMM  C[M,N] = A[M,K] * Bt[N,K]^T   (both bf16, K-contiguous)
// 128x128 tile, BK=32, 4 waves, mfma_f32_16x16x32_bf16, 4x4 frags/wave.
// MODE 0: outb = acc                      (Q/K/V)
// MODE 1: outf = acc + bias[c] + resf     (Wo -> x_attn fp32, into d_out)
// MODE 2: outb = gelu(acc + bias[c])      (W1)
// MODE 3: outf = acc + bias[c] + resf     (W2 -> final fp32, in-place d_out)
// ---------------------------------------------------------------------------
__device__ __forceinline__ float gelu_tanh_f(float v) {
  float u = v + 0.044715f * v * v * v;
  float t = tanhf(0.7978845608028654f * u);
  return 0.5f * v * (1.0f + t);
}

template <int MODE>
__global__ __launch_bounds__(256, 2) void gemm_bt(
    const unsigned short* __restrict__ A, const unsigned short* __restrict__ Bt,
    int M, int N, int K,
    const float* __restrict__ bias, const float* __restrict__ resf,
    float* __restrict__ outf, unsigned short* __restrict__ outb)
{
  __shared__ unsigned short As[128][40];
  __shared__ unsigned short Bs[128][40];
  const int tid = threadIdx.x;
  const int m0 = blockIdx.y * 128, n0 = blockIdx.x * 128;
  const int lane = tid & 63, wid = tid >> 6;
  const int wr = wid >> 1, wc = wid & 1;
  const int l16 = lane & 15, kg = lane >> 4;

  const int ar = tid & 127, ah = tid >> 7;  // staging: row, 16-col half
  const unsigned short* pA = A  + (size_t)(m0 + ar) * K + ah * 16;
  const unsigned short* pB = Bt + (size_t)(n0 + ar) * K + ah * 16;

  f32x4 acc[4][4];
#pragma unroll
  for (int i = 0; i < 4; ++i)
#pragma unroll
    for (int j = 0; j < 4; ++j) acc[i][j] = (f32x4){0.f, 0.f, 0.f, 0.f};

  for (int kt = 0; kt < K; kt += 32) {
    float4 a0 = *(const float4*)(pA);
    float4 a1 = *(const float4*)(pA + 8);
    float4 b0 = *(const float4*)(pB);
    float4 b1 = *(const float4*)(pB + 8);
    pA += 32; pB += 32;
    __syncthreads();
    *(float4*)(&As[ar][ah * 16])     = a0;
    *(float4*)(&As[ar][ah * 16 + 8]) = a1;
    *(float4*)(&Bs[ar][ah * 16])     = b0;
    *(float4*)(&Bs[ar][ah * 16 + 8]) = b1;
    __syncthreads();
    short8 af[4], bfr[4];
#pragma unroll
    for (int i = 0; i < 4; ++i)
      af[i] = *(const short8*)(&As[wr * 64 + i * 16 + l16][kg * 8]);
#pragma unroll
    for (int j = 0; j < 4; ++j)
      bfr[j] = *(const short8*)(&Bs[wc * 64 + j * 16 + l16][kg * 8]);
#pragma unroll
    for (int i = 0; i < 4; ++i)
#pragma unroll
      for (int j = 0; j < 4; ++j)
        acc[i][j] = __builtin_amdgcn_mfma_f32_16x16x32_bf16(af[i], bfr[j], acc[i][j], 0, 0, 0);
  }

#pragma unroll
  for (int i = 0; i < 4; ++i) {
#pragma unroll
    for (int j = 0; j < 4; ++j) {
      const int c = n0 + wc * 64 + j * 16 + l16;
#pragma unroll
      for (int r = 0; r < 4; ++r) {
        const int row = m0 + wr * 64 + i * 16 + kg * 4 + r;
        const size_t idx = (size_t)row * N + c;
        float v = acc[i][j][r];
        if constexpr (MODE == 0) {
          outb[idx] = f2bf(v);
        } else if constexpr (MODE == 1) {
          outf[idx] = v + bias[c] + resf[idx];
        } else if constexpr (MODE == 2) {
          outb[idx] = f2bf(gelu_tanh_f(v + bias[c]));
        } else {  // MODE == 3
          outf[idx] = v + bias[c] + resf[idx];
        }
      }
    }
  }
}

// ---------------------------------------------------------------------------
// Causal flash attention, fp32 math over bf16 Q/K/V.
// 1 wave per (b,h,q-row).  lane d holds q[d] and o[d] (D=64 == wave size).
// grid (S, B*H), block 64.
// ---------------------------------------------------------------------------
__global__ __launch_bounds__(64) void attn_kernel(
    const unsigned short* __restrict__ Qb, const unsigned short* __restrict__ Kb,
    const unsigned short* __restrict__ Vb, unsigned short* __restrict__ ctx)
{
  const int q  = blockIdx.x;
  const int bh = blockIdx.y;
  const int b  = bh >> 4, h = bh & 15;
  const int lane = threadIdx.x;
  const size_t base = ((size_t)b * S_LEN) * EMB + h * HDIM;

  const float qv = bf2f(Qb[base + (size_t)q * EMB + lane]);
  float m = -INFINITY, l = 0.f, o = 0.f;
  const int ntiles = (q >> 6) + 1;

  for (int kt = 0; kt < ntiles; ++kt) {
    const int key = kt * 64 + lane;
    const unsigned short* krow = Kb + base + (size_t)key * EMB;
    float s = 0.f;
#pragma unroll
    for (int d0 = 0; d0 < 64; d0 += 8) {
      uint4 kv = *(const uint4*)(krow + d0);
      float k0 = bf2f((unsigned short)(kv.x & 0xffff));
      float k1 = bf2f((unsigned short)(kv.x >> 16));
      float k2 = bf2f((unsigned short)(kv.y & 0xffff));
      float k3 = bf2f((unsigned short)(kv.y >> 16));
      float k4 = bf2f((unsigned short)(kv.z & 0xffff));
      float k5 = bf2f((unsigned short)(kv.z >> 16));
      float k6 = bf2f((unsigned short)(kv.w & 0xffff));
      float k7 = bf2f((unsigned short)(kv.w >> 16));
      s += __shfl(qv, d0 + 0) * k0 + __shfl(qv, d0 + 1) * k1
         + __shfl(qv, d0 + 2) * k2 + __shfl(qv, d0 + 3) * k3
         + __shfl(qv, d0 + 4) * k4 + __shfl(qv, d0 + 5) * k5
         + __shfl(qv, d0 + 6) * k6 + __shfl(qv, d0 + 7) * k7;
    }
    s *= 0.125f;  // 1/sqrt(64)
    if (key > q) s = -INFINITY;

    float smax = s;
#pragma unroll
    for (int off = 32; off > 0; off >>= 1) smax = fmaxf(smax, __shfl_xor(smax, off));
    const float newm = fmaxf(m, smax);
    const float p = __expf(s - newm);  // masked lanes: exp(-inf)=0
    float psum = p;
#pragma unroll
    for (int off = 32; off > 0; off >>= 1) psum += __shfl_xor(psum, off);
    const float fac = __expf(m - newm);  // first tile: exp(-inf)=0
    l = l * fac + psum;
    o *= fac;
    m = newm;

    const unsigned short* vcol = Vb + base + (size_t)(kt * 64) * EMB + lane;
#pragma unroll 8
    for (int k = 0; k < 64; ++k) {
      float pk = __shfl(p, k);
      o += pk * bf2f(vcol[(size_t)k * EMB]);
    }
  }
  ctx[base + (size_t)q * EMB + lane] = f2bf(o / l);
}

// ---------------------------------------------------------------------------
// Host launcher.  ws layout (bytes):
//   0..2M    wtQ   2..4M wtK   4..6M wtV   6..8M wtO        (bf16 [1024,1024])
//   8..16M   wtW1 (bf16 [4096,1024])   16..24M wtW2 (bf16 [1024,4096])
//   24..32M  h / h2 (bf16 [4096,1024])
//   32..40M  Q   40..48M K   48..56M V   56..64M ctx        (bf16 [4096,1024])
//   32..64M  (reused) gbuf = gelu(h2@W1+b1)  (bf16 [4096,4096])
// x_attn (fp32) lives in d_out and is fully rewritten every call.
// Peak ws use: 64 MB.
// ---------------------------------------------------------------------------
extern "C" void kernel_launch(void* const* d_in, const int* in_sizes, int n_in,
                              void* d_out, int out_size, void* d_ws, size_t ws_size,
                              hipStream_t stream)
{
  const float* x  = (const float*)d_in[0];
  const float* Wq = (const float*)d_in[1];
  const float* Wk = (const float*)d_in[2];
  const float* Wv = (const float*)d_in[3];
  const float* Wo = (const float*)d_in[4];
  const float* bo = (const float*)d_in[5];
  const float* W1 = (const float*)d_in[6];
  const float* b1 = (const float*)d_in[7];
  const float* W2 = (const float*)d_in[8];
  const float* b2 = (const float*)d_in[9];
  const float* g1 = (const float*)d_in[10];
  const float* s1 = (const float*)d_in[11];
  const float* g2 = (const float*)d_in[12];
  const float* s2 = (const float*)d_in[13];

  float* out = (float*)d_out;            // fp32 output; also x_attn scratch
  char* ws = (char*)d_ws;
  const size_t MB = 1024 * 1024;
  unsigned short* wtQ  = (unsigned short*)(ws + 0 * MB);
  unsigned short* wtK  = (unsigned short*)(ws + 2 * MB);
  unsigned short* wtV  = (unsigned short*)(ws + 4 * MB);
  unsigned short* wtO  = (unsigned short*)(ws + 6 * MB);
  unsigned short* wtW1 = (unsigned short*)(ws + 8 * MB);
  unsigned short* wtW2 = (unsigned short*)(ws + 16 * MB);
  unsigned short* h    = (unsigned short*)(ws + 24 * MB);
  unsigned short* Qb   = (unsigned short*)(ws + 32 * MB);
  unsigned short* Kb   = (unsigned short*)(ws + 40 * MB);
  unsigned short* Vb   = (unsigned short*)(ws + 48 * MB);
  unsigned short* ctx  = (unsigned short*)(ws + 56 * MB);
  unsigned short* h2   = h;              // reuse (h dead after QKV GEMMs)
  unsigned short* gbuf = Qb;             // reuse 32..64MB (Q/K/V/ctx dead)

  dim3 tb(32, 8);
  transpose_to_bf16<<<dim3(32, 32),  tb, 0, stream>>>(Wq, wtQ, 1024, 1024);
  transpose_to_bf16<<<dim3(32, 32),  tb, 0, stream>>>(Wk, wtK, 1024, 1024);
  transpose_to_bf16<<<dim3(32, 32),  tb, 0, stream>>>(Wv, wtV, 1024, 1024);
  transpose_to_bf16<<<dim3(32, 32),  tb, 0, stream>>>(Wo, wtO, 1024, 1024);
  transpose_to_bf16<<<dim3(128, 32), tb, 0, stream>>>(W1, wtW1, 1024, 4096);
  transpose_to_bf16<<<dim3(32, 128), tb, 0, stream>>>(W2, wtW2, 4096, 1024);

  ln_kernel<<<MTOT, 256, 0, stream>>>(x, g1, s1, h);

  gemm_bt<0><<<dim3(8, 32), 256, 0, stream>>>(h, wtQ, MTOT, 1024, 1024, nullptr, nullptr, nullptr, Qb);
  gemm_bt<0><<<dim3(8, 32), 256, 0, stream>>>(h, wtK, MTOT, 1024, 1024, nullptr, nullptr, nullptr, Kb);
  gemm_bt<0><<<dim3(8, 32), 256, 0, stream>>>(h, wtV, MTOT, 1024, 1024, nullptr, nullptr, nullptr, Vb);

  attn_kernel<<<dim3(S_LEN, NB * HEADS), 64, 0, stream>>>(Qb, Kb, Vb, ctx);

  // x_attn = x + ctx@Wo + bo  (fp32, into d_out)
  gemm_bt<1><<<dim3(8, 32), 256, 0, stream>>>(ctx, wtO, MTOT, 1024, 1024, bo, x, out, nullptr);

  ln_kernel<<<MTOT, 256, 0, stream>>>(out, g2, s2, h2);

  gemm_bt<2><<<dim3(32, 32), 256, 0, stream>>>(h2, wtW1, MTOT, 4096, 1024, b1, nullptr, nullptr, gbuf);

  // out = x_attn + gbuf@W2 + b2   (in-place read+write of d_out, same-thread)
  gemm_bt<3><<<dim3(8, 32), 256, 0, stream>>>(gbuf, wtW2, MTOT, 1024, 4096, b2, out, out, nullptr);
}

// Round 2
// 516.223 us; speedup vs baseline: 4.7710x; 4.7710x over previous
//
#include <hip/hip_runtime.h>
#include <hip/hip_bf16.h>

typedef __attribute__((ext_vector_type(8))) short short8;
typedef __attribute__((ext_vector_type(4))) float f32x4;

#define EMB   1024
#define DFF   4096
#define S_LEN 2048
#define NB    2
#define MTOT  (NB * S_LEN)   // 4096
#define HEADS 16
#define HDIM  64

__device__ __forceinline__ float bf2f(unsigned short u) {
  return __uint_as_float(((unsigned int)u) << 16);
}
__device__ __forceinline__ unsigned short f2bf(float f) {
  unsigned int x = __float_as_uint(f);
  unsigned int r = (x + 0x7fffu + ((x >> 16) & 1u)) >> 16;  // RN, no NaN inputs here
  return (unsigned short)r;
}

// ---------------------------------------------------------------------------
// Weight fp32 [K,N] -> bf16 [N,K]
// ---------------------------------------------------------------------------
__global__ __launch_bounds__(256) void transpose_to_bf16(
    const float* __restrict__ W, unsigned short* __restrict__ Wt, int K, int N)
{
  __shared__ float t[32][33];
  const int n0 = blockIdx.x * 32, k0 = blockIdx.y * 32;
  const int tx = threadIdx.x, ty = threadIdx.y;
#pragma unroll
  for (int i = 0; i < 4; ++i) {
    int r = ty + i * 8;
    t[r][tx] = W[(size_t)(k0 + r) * N + n0 + tx];
  }
  __syncthreads();
#pragma unroll
  for (int i = 0; i < 4; ++i) {
    int r = ty + i * 8;
    Wt[(size_t)(n0 + r) * K + k0 + tx] = f2bf(t[tx][r]);
  }
}

// ---------------------------------------------------------------------------
// V [token, (h,d)] bf16 -> Vt [(b,h), d, s] bf16   (PV B-operand K-contiguous)
// grid (S/32, HDIM/32, NB*HEADS), block (32,8)
// ---------------------------------------------------------------------------
__global__ __launch_bounds__(256) void transpose_v(
    const unsigned short* __restrict__ Vb, unsigned short* __restrict__ Vt)
{
  __shared__ unsigned short t[32][33];
  const int s0 = blockIdx.x * 32, d0 = blockIdx.y * 32, bh = blockIdx.z;
  const int b = bh >> 4, h = bh & 15;
  const int tx = threadIdx.x, ty = threadIdx.y;
#pragma unroll
  for (int i = 0; i < 4; ++i) {
    int r = ty + i * 8;  // s offset
    t[r][tx] = Vb[((size_t)(b * S_LEN + s0 + r)) * EMB + h * HDIM + d0 + tx];
  }
  __syncthreads();
#pragma unroll
  for (int i = 0; i < 4; ++i) {
    int r = ty + i * 8;  // d offset
    Vt[((size_t)bh * HDIM + d0 + r) * S_LEN + s0 + tx] = t[tx][r];
  }
}

// ---------------------------------------------------------------------------
// LayerNorm: fp32 [rows,1024] -> bf16 [rows,1024].  block 256, grid rows.
// ---------------------------------------------------------------------------
__global__ __launch_bounds__(256) void ln_kernel(
    const float* __restrict__ X, const float* __restrict__ g,
    const float* __restrict__ sh, unsigned short* __restrict__ H)
{
  const int row = blockIdx.x, t = threadIdx.x;
  const float* xr = X + (size_t)row * EMB;
  float4 v = *(const float4*)(xr + t * 4);
  float s  = v.x + v.y + v.z + v.w;
  float ss = v.x * v.x + v.y * v.y + v.z * v.z + v.w * v.w;
#pragma unroll
  for (int off = 32; off > 0; off >>= 1) {
    s  += __shfl_xor(s, off);
    ss += __shfl_xor(ss, off);
  }
  __shared__ float rs[4], rss[4];
  const int wid = t >> 6;
  if ((t & 63) == 0) { rs[wid] = s; rss[wid] = ss; }
  __syncthreads();
  s  = rs[0] + rs[1] + rs[2] + rs[3];
  ss = rss[0] + rss[1] + rss[2] + rss[3];
  const float mean = s * (1.f / EMB);
  const float var  = ss * (1.f / EMB) - mean * mean;
  const float rstd = rsqrtf(var + 1e-5f);
  float4 gv = *(const float4*)(g + t * 4);
  float4 sv = *(const float4*)(sh + t * 4);
  ushort4 o;
  o.x = f2bf((v.x - mean) * rstd * gv.x + sv.x);
  o.y = f2bf((v.y - mean) * rstd * gv.y + sv.y);
  o.z = f2bf((v.z - mean) * rstd * gv.z + sv.z);
  o.w = f2bf((v.w - mean) * rstd * gv.w + sv.w);
  *(ushort4*)(H + (size_t)row * EMB + t * 4) = o;
}

// ---------------------------------------------------------------------------
// GEMM  C[M,N] = A[M,K] * Bt[N,K]^T   (both bf16, K-contiguous)
// ---------------------------------------------------------------------------
__device__ __forceinline__ float gelu_tanh_f(float v) {
  float u = v + 0.044715f * v * v * v;
  float t = tanhf(0.7978845608028654f * u);
  return 0.5f * v * (1.0f + t);
}

template <int MODE>
__global__ __launch_bounds__(256, 2) void gemm_bt(
    const unsigned short* __restrict__ A, const unsigned short* __restrict__ Bt,
    int M, int N, int K,
    const float* __restrict__ bias, const float* __restrict__ resf,
    float* __restrict__ outf, unsigned short* __restrict__ outb)
{
  __shared__ unsigned short As[128][40];
  __shared__ unsigned short Bs[128][40];
  const int tid = threadIdx.x;
  const int m0 = blockIdx.y * 128, n0 = blockIdx.x * 128;
  const int lane = tid & 63, wid = tid >> 6;
  const int wr = wid >> 1, wc = wid & 1;
  const int l16 = lane & 15, kg = lane >> 4;

  const int ar = tid & 127, ah = tid >> 7;
  const unsigned short* pA = A  + (size_t)(m0 + ar) * K + ah * 16;
  const unsigned short* pB = Bt + (size_t)(n0 + ar) * K + ah * 16;

  f32x4 acc[4][4];
#pragma unroll
  for (int i = 0; i < 4; ++i)
#pragma unroll
    for (int j = 0; j < 4; ++j) acc[i][j] = (f32x4){0.f, 0.f, 0.f, 0.f};

  for (int kt = 0; kt < K; kt += 32) {
    float4 a0 = *(const float4*)(pA);
    float4 a1 = *(const float4*)(pA + 8);
    float4 b0 = *(const float4*)(pB);
    float4 b1 = *(const float4*)(pB + 8);
    pA += 32; pB += 32;
    __syncthreads();
    *(float4*)(&As[ar][ah * 16])     = a0;
    *(float4*)(&As[ar][ah * 16 + 8]) = a1;
    *(float4*)(&Bs[ar][ah * 16])     = b0;
    *(float4*)(&Bs[ar][ah * 16 + 8]) = b1;
    __syncthreads();
    short8 af[4], bfr[4];
#pragma unroll
    for (int i = 0; i < 4; ++i)
      af[i] = *(const short8*)(&As[wr * 64 + i * 16 + l16][kg * 8]);
#pragma unroll
    for (int j = 0; j < 4; ++j)
      bfr[j] = *(const short8*)(&Bs[wc * 64 + j * 16 + l16][kg * 8]);
#pragma unroll
    for (int i = 0; i < 4; ++i)
#pragma unroll
      for (int j = 0; j < 4; ++j)
        acc[i][j] = __builtin_amdgcn_mfma_f32_16x16x32_bf16(af[i], bfr[j], acc[i][j], 0, 0, 0);
  }

#pragma unroll
  for (int i = 0; i < 4; ++i) {
#pragma unroll
    for (int j = 0; j < 4; ++j) {
      const int c = n0 + wc * 64 + j * 16 + l16;
#pragma unroll
      for (int r = 0; r < 4; ++r) {
        const int row = m0 + wr * 64 + i * 16 + kg * 4 + r;
        const size_t idx = (size_t)row * N + c;
        float v = acc[i][j][r];
        if constexpr (MODE == 0) {
          outb[idx] = f2bf(v);
        } else if constexpr (MODE == 1) {
          outf[idx] = v + bias[c] + resf[idx];
        } else if constexpr (MODE == 2) {
          outb[idx] = f2bf(gelu_tanh_f(v + bias[c]));
        } else {  // MODE == 3
          outf[idx] = v + bias[c] + resf[idx];
        }
      }
    }
  }
}

// ---------------------------------------------------------------------------
// MFMA causal flash attention.
// Block = 256 thr (4 waves) handles 64 q-rows of one (b,h); wave wv owns
// q-rows wv*16..wv*16+15.  KV tiles of 64 staged in LDS.  grid (S/64, B*H).
// S-tile: mfma(Qfrag, Kfrag) -> lane holds S[kg*4+r][j*16+l16].
// P re-laid out through per-wave LDS tile into PV A-fragments.
// PV: mfma(Pfrag, VtFrag) with Vt tile [d][keys] (K-contiguous).
// ---------------------------------------------------------------------------
__global__ __launch_bounds__(256) void attn_mfma(
    const unsigned short* __restrict__ Qb, const unsigned short* __restrict__ Kb,
    const unsigned short* __restrict__ Vt, unsigned short* __restrict__ ctx)
{
  __shared__ unsigned short Ks[64][72];
  __shared__ unsigned short Vs[64][72];
  __shared__ unsigned short Ps[4][16][72];

  const int tid  = threadIdx.x;
  const int lane = tid & 63, wv = tid >> 6;
  const int l16  = lane & 15, kg = lane >> 4;
  const int q0   = blockIdx.x * 64;
  const int bh   = blockIdx.y;
  const int b    = bh >> 4, h = bh & 15;

  const size_t qkbase = ((size_t)b * S_LEN) * EMB + h * HDIM;  // token-major
  const size_t vtbase = ((size_t)bh * HDIM) * S_LEN;           // [d][s]

  // Q fragments (held in registers for the whole kernel)
  short8 qf[2];
  {
    const unsigned short* qrow = Qb + qkbase + (size_t)(q0 + wv * 16 + l16) * EMB;
    qf[0] = *(const short8*)(qrow + kg * 8);
    qf[1] = *(const short8*)(qrow + 32 + kg * 8);
  }

  f32x4 o[4];
#pragma unroll
  for (int dt = 0; dt < 4; ++dt) o[dt] = (f32x4){0.f, 0.f, 0.f, 0.f};
  float m[4], l[4];
#pragma unroll
  for (int r = 0; r < 4; ++r) { m[r] = -1e30f; l[r] = 0.f; }

  const int srow = tid >> 2;            // 0..63 staging row
  const int scol = (tid & 3) * 16;      // 0,16,32,48

  const int ntiles = blockIdx.x + 1;
  for (int kt = 0; kt < ntiles; ++kt) {
    // ---- stage K and Vt tiles ----
    const unsigned short* ksrc = Kb + qkbase + (size_t)(kt * 64 + srow) * EMB + scol;
    const unsigned short* vsrc = Vt + vtbase + (size_t)srow * S_LEN + kt * 64 + scol;
    short8 k0 = *(const short8*)(ksrc);
    short8 k1 = *(const short8*)(ksrc + 8);
    short8 v0 = *(const short8*)(vsrc);
    short8 v1 = *(const short8*)(vsrc + 8);
    __syncthreads();   // previous iteration's reads done
    *(short8*)(&Ks[srow][scol])     = k0;
    *(short8*)(&Ks[srow][scol + 8]) = k1;
    *(short8*)(&Vs[srow][scol])     = v0;
    *(short8*)(&Vs[srow][scol + 8]) = v1;
    __syncthreads();

    // ---- S = Q K^T (per wave: 16 q x 64 keys) ----
    f32x4 sa[4];
#pragma unroll
    for (int j = 0; j < 4; ++j) {
      sa[j] = (f32x4){0.f, 0.f, 0.f, 0.f};
      short8 kf0 = *(const short8*)(&Ks[j * 16 + l16][kg * 8]);
      short8 kf1 = *(const short8*)(&Ks[j * 16 + l16][32 + kg * 8]);
      sa[j] = __builtin_amdgcn_mfma_f32_16x16x32_bf16(qf[0], kf0, sa[j], 0, 0, 0);
      sa[j] = __builtin_amdgcn_mfma_f32_16x16x32_bf16(qf[1], kf1, sa[j], 0, 0, 0);
    }

    // ---- online softmax (per q-row = kg*4+r) ----
    const bool diag = (kt == blockIdx.x);
    float fac[4];
#pragma unroll
    for (int r = 0; r < 4; ++r) {
      const int qloc = wv * 16 + kg * 4 + r;
#pragma unroll
      for (int j = 0; j < 4; ++j) {
        float v = sa[j][r] * 0.125f;
        if (diag && (j * 16 + l16) > qloc) v = -1e30f;
        sa[j][r] = v;
      }
      float mx = fmaxf(fmaxf(sa[0][r], sa[1][r]), fmaxf(sa[2][r], sa[3][r]));
#pragma unroll
      for (int off = 1; off < 16; off <<= 1) mx = fmaxf(mx, __shfl_xor(mx, off));
      const float mn = fmaxf(m[r], mx);
      fac[r] = __expf(m[r] - mn);
      m[r] = mn;
      float ps = 0.f;
#pragma unroll
      for (int j = 0; j < 4; ++j) {
        float p = __expf(sa[j][r] - mn);
        sa[j][r] = p;
        ps += p;
      }
#pragma unroll
      for (int off = 1; off < 16; off <<= 1) ps += __shfl_xor(ps, off);
      l[r] = l[r] * fac[r] + ps;
    }

    // ---- write P (bf16) to per-wave LDS tile ----
#pragma unroll
    for (int j = 0; j < 4; ++j)
#pragma unroll
      for (int r = 0; r < 4; ++r)
        Ps[wv][kg * 4 + r][j * 16 + l16] = f2bf(sa[j][r]);

    // ---- rescale o, then PV ----
#pragma unroll
    for (int dt = 0; dt < 4; ++dt)
#pragma unroll
      for (int r = 0; r < 4; ++r) o[dt][r] *= fac[r];

    short8 pf0 = *(const short8*)(&Ps[wv][l16][kg * 8]);
    short8 pf1 = *(const short8*)(&Ps[wv][l16][32 + kg * 8]);
#pragma unroll
    for (int dt = 0; dt < 4; ++dt) {
      short8 vf0 = *(const short8*)(&Vs[dt * 16 + l16][kg * 8]);
      short8 vf1 = *(const short8*)(&Vs[dt * 16 + l16][32 + kg * 8]);
      o[dt] = __builtin_amdgcn_mfma_f32_16x16x32_bf16(pf0, vf0, o[dt], 0, 0, 0);
      o[dt] = __builtin_amdgcn_mfma_f32_16x16x32_bf16(pf1, vf1, o[dt], 0, 0, 0);
    }
  }

  // ---- final: ctx = o / l ----
#pragma unroll
  for (int dt = 0; dt < 4; ++dt)
#pragma unroll
    for (int r = 0; r < 4; ++r) {
      const int qrow = q0 + wv * 16 + kg * 4 + r;
      ctx[qkbase + (size_t)qrow * EMB + dt * 16 + l16] = f2bf(o[dt][r] / l[r]);
    }
}

// ---------------------------------------------------------------------------
// Host launcher.  ws layout (bytes, MB units):
//   0..2 wtQ | 2..4 wtK | 4..6 wtV | 6..8 wtO | 8..16 wtW1 | 16..24 wtW2
//   24..32  h (ln1 out) -> later ctx (attn out) -> later h2 (ln2 out)
//   32..40 Qb | 40..48 Kb | 48..56 Vb | 56..64 Vt
//   32..64  (reused) gbuf = gelu(h2@W1+b1)
// Peak ws use: 64 MB.  x_attn (fp32) lives in d_out.
// ---------------------------------------------------------------------------
extern "C" void kernel_launch(void* const* d_in, const int* in_sizes, int n_in,
                              void* d_out, int out_size, void* d_ws, size_t ws_size,
                              hipStream_t stream)
{
  const float* x  = (const float*)d_in[0];
  const float* Wq = (const float*)d_in[1];
  const float* Wk = (const float*)d_in[2];
  const float* Wv = (const float*)d_in[3];
  const float* Wo = (const float*)d_in[4];
  const float* bo = (const float*)d_in[5];
  const float* W1 = (const float*)d_in[6];
  const float* b1 = (const float*)d_in[7];
  const float* W2 = (const float*)d_in[8];
  const float* b2 = (const float*)d_in[9];
  const float* g1 = (const float*)d_in[10];
  const float* s1 = (const float*)d_in[11];
  const float* g2 = (const float*)d_in[12];
  const float* s2 = (const float*)d_in[13];

  float* out = (float*)d_out;
  char* ws = (char*)d_ws;
  const size_t MB = 1024 * 1024;
  unsigned short* wtQ  = (unsigned short*)(ws + 0 * MB);
  unsigned short* wtK  = (unsigned short*)(ws + 2 * MB);
  unsigned short* wtV  = (unsigned short*)(ws + 4 * MB);
  unsigned short* wtO  = (unsigned short*)(ws + 6 * MB);
  unsigned short* wtW1 = (unsigned short*)(ws + 8 * MB);
  unsigned short* wtW2 = (unsigned short*)(ws + 16 * MB);
  unsigned short* h    = (unsigned short*)(ws + 24 * MB);
  unsigned short* Qb   = (unsigned short*)(ws + 32 * MB);
  unsigned short* Kb   = (unsigned short*)(ws + 40 * MB);
  unsigned short* Vb   = (unsigned short*)(ws + 48 * MB);
  unsigned short* Vt   = (unsigned short*)(ws + 56 * MB);
  unsigned short* ctxb = h;              // reuse (h dead after QKV GEMMs)
  unsigned short* h2   = h;              // reuse (ctx dead after Wo GEMM)
  unsigned short* gbuf = Qb;             // reuse 32..64MB

  dim3 tb(32, 8);
  transpose_to_bf16<<<dim3(32, 32),  tb, 0, stream>>>(Wq, wtQ, 1024, 1024);
  transpose_to_bf16<<<dim3(32, 32),  tb, 0, stream>>>(Wk, wtK, 1024, 1024);
  transpose_to_bf16<<<dim3(32, 32),  tb, 0, stream>>>(Wv, wtV, 1024, 1024);
  transpose_to_bf16<<<dim3(32, 32),  tb, 0, stream>>>(Wo, wtO, 1024, 1024);
  transpose_to_bf16<<<dim3(128, 32), tb, 0, stream>>>(W1, wtW1, 1024, 4096);
  transpose_to_bf16<<<dim3(32, 128), tb, 0, stream>>>(W2, wtW2, 4096, 1024);

  ln_kernel<<<MTOT, 256, 0, stream>>>(x, g1, s1, h);

  gemm_bt<0><<<dim3(8, 32), 256, 0, stream>>>(h, wtQ, MTOT, 1024, 1024, nullptr, nullptr, nullptr, Qb);
  gemm_bt<0><<<dim3(8, 32), 256, 0, stream>>>(h, wtK, MTOT, 1024, 1024, nullptr, nullptr, nullptr, Kb);
  gemm_bt<0><<<dim3(8, 32), 256, 0, stream>>>(h, wtV, MTOT, 1024, 1024, nullptr, nullptr, nullptr, Vb);

  transpose_v<<<dim3(64, 2, 32), tb, 0, stream>>>(Vb, Vt);

  attn_mfma<<<dim3(32, 32), 256, 0, stream>>>(Qb, Kb, Vt, ctxb);

  // x_attn = x + ctx@Wo + bo  (fp32, into d_out)
  gemm_bt<1><<<dim3(8, 32), 256, 0, stream>>>(ctxb, wtO, MTOT, 1024, 1024, bo, x, out, nullptr);

  ln_kernel<<<MTOT, 256, 0, stream>>>(out, g2, s2, h2);

  gemm_bt<2><<<dim3(32, 32), 256, 0, stream>>>(h2, wtW1, MTOT, 4096, 1024, b1, nullptr, nullptr, gbuf);

  // out = x_attn + gbuf@W2 + b2
  gemm_bt<3><<<dim3(8, 32), 256, 0, stream>>>(gbuf, wtW2, MTOT, 1024, 4096, b2, out, out, nullptr);
}

// Round 3
// 342.850 us; speedup vs baseline: 7.1836x; 1.5057x over previous
//
#include <hip/hip_runtime.h>
#include <hip/hip_bf16.h>

typedef __attribute__((ext_vector_type(8))) short short8;
typedef __attribute__((ext_vector_type(4))) float f32x4;

#define EMB   1024
#define DFF   4096
#define S_LEN 2048
#define NB    2
#define MTOT  (NB * S_LEN)   // 4096
#define HEADS 16
#define HDIM  64
#define QKVN  3072           // fused QKV output width
#define BK    32

__device__ __forceinline__ float bf2f(unsigned short u) {
  return __uint_as_float(((unsigned int)u) << 16);
}
__device__ __forceinline__ unsigned short f2bf(float f) {
  unsigned int x = __float_as_uint(f);
  unsigned int r = (x + 0x7fffu + ((x >> 16) & 1u)) >> 16;  // RN
  return (unsigned short)r;
}

// async global->LDS, 16B per lane; lptr must be wave-uniform (HW adds lane*16)
__device__ __forceinline__ void gl_lds16(const unsigned short* g, unsigned short* l) {
  __builtin_amdgcn_global_load_lds(
      (const __attribute__((address_space(1))) unsigned int*)g,
      (__attribute__((address_space(3))) unsigned int*)l, 16, 0, 0);
}

// ---------------------------------------------------------------------------
// Weight fp32 [K,N] -> bf16 [N,K]
// ---------------------------------------------------------------------------
__global__ __launch_bounds__(256) void transpose_to_bf16(
    const float* __restrict__ W, unsigned short* __restrict__ Wt, int K, int N)
{
  __shared__ float t[32][33];
  const int n0 = blockIdx.x * 32, k0 = blockIdx.y * 32;
  const int tx = threadIdx.x, ty = threadIdx.y;
#pragma unroll
  for (int i = 0; i < 4; ++i) {
    int r = ty + i * 8;
    t[r][tx] = W[(size_t)(k0 + r) * N + n0 + tx];
  }
  __syncthreads();
#pragma unroll
  for (int i = 0; i < 4; ++i) {
    int r = ty + i * 8;
    Wt[(size_t)(n0 + r) * K + k0 + tx] = f2bf(t[tx][r]);
  }
}

// ---------------------------------------------------------------------------
// V slice of fused qkv [token, 3072] -> Vt [(b,h), d, s]
// grid (S/32, HDIM/32, NB*HEADS), block (32,8)
// ---------------------------------------------------------------------------
__global__ __launch_bounds__(256) void transpose_v(
    const unsigned short* __restrict__ qkv, unsigned short* __restrict__ Vt)
{
  __shared__ unsigned short t[32][33];
  const int s0 = blockIdx.x * 32, d0 = blockIdx.y * 32, bh = blockIdx.z;
  const int b = bh >> 4, h = bh & 15;
  const int tx = threadIdx.x, ty = threadIdx.y;
#pragma unroll
  for (int i = 0; i < 4; ++i) {
    int r = ty + i * 8;  // s offset
    t[r][tx] = qkv[((size_t)(b * S_LEN + s0 + r)) * QKVN + 2048 + h * HDIM + d0 + tx];
  }
  __syncthreads();
#pragma unroll
  for (int i = 0; i < 4; ++i) {
    int r = ty + i * 8;  // d offset
    Vt[((size_t)bh * HDIM + d0 + r) * S_LEN + s0 + tx] = t[tx][r];
  }
}

// ---------------------------------------------------------------------------
// LayerNorm: fp32 [rows,1024] -> bf16 [rows,1024].  block 256, grid rows.
// ---------------------------------------------------------------------------
__global__ __launch_bounds__(256) void ln_kernel(
    const float* __restrict__ X, const float* __restrict__ g,
    const float* __restrict__ sh, unsigned short* __restrict__ H)
{
  const int row = blockIdx.x, t = threadIdx.x;
  const float* xr = X + (size_t)row * EMB;
  float4 v = *(const float4*)(xr + t * 4);
  float s  = v.x + v.y + v.z + v.w;
  float ss = v.x * v.x + v.y * v.y + v.z * v.z + v.w * v.w;
#pragma unroll
  for (int off = 32; off > 0; off >>= 1) {
    s  += __shfl_xor(s, off);
    ss += __shfl_xor(ss, off);
  }
  __shared__ float rs[4], rss[4];
  const int wid = t >> 6;
  if ((t & 63) == 0) { rs[wid] = s; rss[wid] = ss; }
  __syncthreads();
  s  = rs[0] + rs[1] + rs[2] + rs[3];
  ss = rss[0] + rss[1] + rss[2] + rss[3];
  const float mean = s * (1.f / EMB);
  const float var  = ss * (1.f / EMB) - mean * mean;
  const float rstd = rsqrtf(var + 1e-5f);
  float4 gv = *(const float4*)(g + t * 4);
  float4 sv = *(const float4*)(sh + t * 4);
  ushort4 o;
  o.x = f2bf((v.x - mean) * rstd * gv.x + sv.x);
  o.y = f2bf((v.y - mean) * rstd * gv.y + sv.y);
  o.z = f2bf((v.z - mean) * rstd * gv.z + sv.z);
  o.w = f2bf((v.w - mean) * rstd * gv.w + sv.w);
  *(ushort4*)(H + (size_t)row * EMB + t * 4) = o;
}

// ---------------------------------------------------------------------------
// GEMM  C[M,N] = A[M,K] * Bt[N,K]^T   (bf16, K-contiguous operands)
// BM=128, BN in {128,64}, BK=32, 4 waves, global_load_lds double-buffered.
// MODE 0: outb = acc
// MODE 1: outf = acc + bias[c] + resf
// MODE 2: outb = gelu(acc + bias[c])
// MODE 3: outf = acc + bias[c] + resf   (in-place ok, same-thread idx)
// ---------------------------------------------------------------------------
__device__ __forceinline__ float gelu_tanh_f(float v) {
  float u = v + 0.044715f * v * v * v;
  float t = tanhf(0.7978845608028654f * u);
  return 0.5f * v * (1.0f + t);
}

template <int MODE, int BN>
__global__ __launch_bounds__(256, 2) void gemm_gl(
    const unsigned short* __restrict__ A, const unsigned short* __restrict__ Bt,
    int M, int N, int K,
    const float* __restrict__ bias, const float* __restrict__ resf,
    float* __restrict__ outf, unsigned short* __restrict__ outb)
{
  constexpr int NFRAG = BN / 32;         // col fragments per wave
  __shared__ unsigned short As[2][128 * BK];
  __shared__ unsigned short Bs[2][BN * BK];

  const int tid = threadIdx.x;
  const int lane = tid & 63, wid = tid >> 6;
  const int m0 = blockIdx.y * 128, n0 = blockIdx.x * BN;
  const int wr = wid >> 1, wc = wid & 1;
  const int l16 = lane & 15, kg = lane >> 4;

  // staging lane coords within a 16-row x 32-col chunk (1024B, 64 lanes x 16B)
  const int sr = lane >> 2;
  const int sc = (lane & 3) * 8;

  const unsigned short* Abase = A + (size_t)m0 * K;
  const unsigned short* Bbase = Bt + (size_t)n0 * K;

  f32x4 acc[4][NFRAG];
#pragma unroll
  for (int i = 0; i < 4; ++i)
#pragma unroll
    for (int j = 0; j < NFRAG; ++j) acc[i][j] = (f32x4){0.f, 0.f, 0.f, 0.f};

  const int nt = K / BK;

#define STAGE(buf, t)                                                          \
  do {                                                                         \
    const int k0_ = (t) * BK;                                                  \
    _Pragma("unroll")                                                          \
    for (int i_ = 0; i_ < 2; ++i_) {                                           \
      const int chunk_ = wid * 2 + i_;                                         \
      gl_lds16(Abase + (size_t)(chunk_ * 16 + sr) * K + k0_ + sc,              \
               &As[buf][0] + chunk_ * 512);                                    \
    }                                                                          \
    _Pragma("unroll")                                                          \
    for (int i_ = 0; i_ < BN / 64; ++i_) {                                     \
      const int chunk_ = wid * (BN / 64) + i_;                                 \
      gl_lds16(Bbase + (size_t)(chunk_ * 16 + sr) * K + k0_ + sc,              \
               &Bs[buf][0] + chunk_ * 512);                                    \
    }                                                                          \
  } while (0)

  STAGE(0, 0);
  __syncthreads();
  int cur = 0;
  for (int t = 0; t < nt; ++t) {
    if (t + 1 < nt) STAGE(cur ^ 1, t + 1);
    short8 af[4], bfr[NFRAG];
#pragma unroll
    for (int i = 0; i < 4; ++i)
      af[i] = *(const short8*)(&As[cur][(wr * 64 + i * 16 + l16) * BK + kg * 8]);
#pragma unroll
    for (int j = 0; j < NFRAG; ++j)
      bfr[j] = *(const short8*)(&Bs[cur][(wc * (BN / 2) + j * 16 + l16) * BK + kg * 8]);
#pragma unroll
    for (int i = 0; i < 4; ++i)
#pragma unroll
      for (int j = 0; j < NFRAG; ++j)
        acc[i][j] = __builtin_amdgcn_mfma_f32_16x16x32_bf16(af[i], bfr[j], acc[i][j], 0, 0, 0);
    __syncthreads();   // drains vmcnt (prefetch) + lgkm, then barrier
    cur ^= 1;
  }
#undef STAGE

#pragma unroll
  for (int i = 0; i < 4; ++i) {
#pragma unroll
    for (int j = 0; j < NFRAG; ++j) {
      const int c = n0 + wc * (BN / 2) + j * 16 + l16;
#pragma unroll
      for (int r = 0; r < 4; ++r) {
        const int row = m0 + wr * 64 + i * 16 + kg * 4 + r;
        const size_t idx = (size_t)row * N + c;
        float v = acc[i][j][r];
        if constexpr (MODE == 0) {
          outb[idx] = f2bf(v);
        } else if constexpr (MODE == 1) {
          outf[idx] = v + bias[c] + resf[idx];
        } else if constexpr (MODE == 2) {
          outb[idx] = f2bf(gelu_tanh_f(v + bias[c]));
        } else {
          outf[idx] = v + bias[c] + resf[idx];
        }
      }
    }
  }
}

// ---------------------------------------------------------------------------
// MFMA causal flash attention.  Q,K from fused qkv [token,3072]; V from Vt.
// Block = 4 waves = 64 q-rows of one (b,h).  grid (S/64, B*H).
// ---------------------------------------------------------------------------
__global__ __launch_bounds__(256) void attn_mfma(
    const unsigned short* __restrict__ qkv, const unsigned short* __restrict__ Vt,
    unsigned short* __restrict__ ctx)
{
  __shared__ unsigned short Ks[64][72];
  __shared__ unsigned short Vs[64][72];
  __shared__ unsigned short Ps[4][16][72];

  const int tid  = threadIdx.x;
  const int lane = tid & 63, wv = tid >> 6;
  const int l16  = lane & 15, kg = lane >> 4;
  const int q0   = blockIdx.x * 64;
  const int bh   = blockIdx.y;
  const int b    = bh >> 4, h = bh & 15;

  const size_t qbase  = ((size_t)b * S_LEN) * QKVN + h * HDIM;
  const size_t kbase  = qbase + 1024;
  const size_t vtbase = ((size_t)bh * HDIM) * S_LEN;
  const size_t cbase  = ((size_t)b * S_LEN) * EMB + h * HDIM;

  short8 qf[2];
  {
    const unsigned short* qrow = qkv + qbase + (size_t)(q0 + wv * 16 + l16) * QKVN;
    qf[0] = *(const short8*)(qrow + kg * 8);
    qf[1] = *(const short8*)(qrow + 32 + kg * 8);
  }

  f32x4 o[4];
#pragma unroll
  for (int dt = 0; dt < 4; ++dt) o[dt] = (f32x4){0.f, 0.f, 0.f, 0.f};
  float m[4], l[4];
#pragma unroll
  for (int r = 0; r < 4; ++r) { m[r] = -1e30f; l[r] = 0.f; }

  const int srow = tid >> 2;
  const int scol = (tid & 3) * 16;

  const int ntiles = blockIdx.x + 1;
  for (int kt = 0; kt < ntiles; ++kt) {
    const unsigned short* ksrc = qkv + kbase + (size_t)(kt * 64 + srow) * QKVN + scol;
    const unsigned short* vsrc = Vt + vtbase + (size_t)srow * S_LEN + kt * 64 + scol;
    short8 k0 = *(const short8*)(ksrc);
    short8 k1 = *(const short8*)(ksrc + 8);
    short8 v0 = *(const short8*)(vsrc);
    short8 v1 = *(const short8*)(vsrc + 8);
    __syncthreads();
    *(short8*)(&Ks[srow][scol])     = k0;
    *(short8*)(&Ks[srow][scol + 8]) = k1;
    *(short8*)(&Vs[srow][scol])     = v0;
    *(short8*)(&Vs[srow][scol + 8]) = v1;
    __syncthreads();

    f32x4 sa[4];
#pragma unroll
    for (int j = 0; j < 4; ++j) {
      sa[j] = (f32x4){0.f, 0.f, 0.f, 0.f};
      short8 kf0 = *(const short8*)(&Ks[j * 16 + l16][kg * 8]);
      short8 kf1 = *(const short8*)(&Ks[j * 16 + l16][32 + kg * 8]);
      sa[j] = __builtin_amdgcn_mfma_f32_16x16x32_bf16(qf[0], kf0, sa[j], 0, 0, 0);
      sa[j] = __builtin_amdgcn_mfma_f32_16x16x32_bf16(qf[1], kf1, sa[j], 0, 0, 0);
    }

    const bool diag = (kt == blockIdx.x);
    float fac[4];
#pragma unroll
    for (int r = 0; r < 4; ++r) {
      const int qloc = wv * 16 + kg * 4 + r;
#pragma unroll
      for (int j = 0; j < 4; ++j) {
        float v = sa[j][r] * 0.125f;
        if (diag && (j * 16 + l16) > qloc) v = -1e30f;
        sa[j][r] = v;
      }
      float mx = fmaxf(fmaxf(sa[0][r], sa[1][r]), fmaxf(sa[2][r], sa[3][r]));
#pragma unroll
      for (int off = 1; off < 16; off <<= 1) mx = fmaxf(mx, __shfl_xor(mx, off));
      const float mn = fmaxf(m[r], mx);
      fac[r] = __expf(m[r] - mn);
      m[r] = mn;
      float ps = 0.f;
#pragma unroll
      for (int j = 0; j < 4; ++j) {
        float p = __expf(sa[j][r] - mn);
        sa[j][r] = p;
        ps += p;
      }
#pragma unroll
      for (int off = 1; off < 16; off <<= 1) ps += __shfl_xor(ps, off);
      l[r] = l[r] * fac[r] + ps;
    }

#pragma unroll
    for (int j = 0; j < 4; ++j)
#pragma unroll
      for (int r = 0; r < 4; ++r)
        Ps[wv][kg * 4 + r][j * 16 + l16] = f2bf(sa[j][r]);

#pragma unroll
    for (int dt = 0; dt < 4; ++dt)
#pragma unroll
      for (int r = 0; r < 4; ++r) o[dt][r] *= fac[r];

    short8 pf0 = *(const short8*)(&Ps[wv][l16][kg * 8]);
    short8 pf1 = *(const short8*)(&Ps[wv][l16][32 + kg * 8]);
#pragma unroll
    for (int dt = 0; dt < 4; ++dt) {
      short8 vf0 = *(const short8*)(&Vs[dt * 16 + l16][kg * 8]);
      short8 vf1 = *(const short8*)(&Vs[dt * 16 + l16][32 + kg * 8]);
      o[dt] = __builtin_amdgcn_mfma_f32_16x16x32_bf16(pf0, vf0, o[dt], 0, 0, 0);
      o[dt] = __builtin_amdgcn_mfma_f32_16x16x32_bf16(pf1, vf1, o[dt], 0, 0, 0);
    }
  }

#pragma unroll
  for (int dt = 0; dt < 4; ++dt)
#pragma unroll
    for (int r = 0; r < 4; ++r) {
      const int qrow = q0 + wv * 16 + kg * 4 + r;
      ctx[cbase + (size_t)qrow * EMB + dt * 16 + l16] = f2bf(o[dt][r] / l[r]);
    }
}

// ---------------------------------------------------------------------------
// ws layout (MB): 0-2 wtQ | 2-4 wtK | 4-6 wtV (contiguous 0-6 = fused QKV Bt)
//   6-8 wtO | 8-16 wtW1 | 16-24 wtW2
//   24-32 h (ln1) -> ctx (attn) -> h2 (ln2)
//   32-56 qkv [4096,3072] | 56-64 Vt | 32-64 gbuf (after attn)
// x_attn fp32 lives in d_out.  Peak ws: 64 MB.
// ---------------------------------------------------------------------------
extern "C" void kernel_launch(void* const* d_in, const int* in_sizes, int n_in,
                              void* d_out, int out_size, void* d_ws, size_t ws_size,
                              hipStream_t stream)
{
  const float* x  = (const float*)d_in[0];
  const float* Wq = (const float*)d_in[1];
  const float* Wk = (const float*)d_in[2];
  const float* Wv = (const float*)d_in[3];
  const float* Wo = (const float*)d_in[4];
  const float* bo = (const float*)d_in[5];
  const float* W1 = (const float*)d_in[6];
  const float* b1 = (const float*)d_in[7];
  const float* W2 = (const float*)d_in[8];
  const float* b2 = (const float*)d_in[9];
  const float* g1 = (const float*)d_in[10];
  const float* s1 = (const float*)d_in[11];
  const float* g2 = (const float*)d_in[12];
  const float* s2 = (const float*)d_in[13];

  float* out = (float*)d_out;
  char* ws = (char*)d_ws;
  const size_t MB = 1024 * 1024;
  unsigned short* wtQ  = (unsigned short*)(ws + 0 * MB);
  unsigned short* wtK  = (unsigned short*)(ws + 2 * MB);
  unsigned short* wtV  = (unsigned short*)(ws + 4 * MB);
  unsigned short* wtO  = (unsigned short*)(ws + 6 * MB);
  unsigned short* wtW1 = (unsigned short*)(ws + 8 * MB);
  unsigned short* wtW2 = (unsigned short*)(ws + 16 * MB);
  unsigned short* h    = (unsigned short*)(ws + 24 * MB);
  unsigned short* qkv  = (unsigned short*)(ws + 32 * MB);
  unsigned short* Vt   = (unsigned short*)(ws + 56 * MB);
  unsigned short* ctxb = h;
  unsigned short* h2   = h;
  unsigned short* gbuf = qkv;            // reuse 32..64MB after attn

  dim3 tb(32, 8);
  transpose_to_bf16<<<dim3(32, 32),  tb, 0, stream>>>(Wq, wtQ, 1024, 1024);
  transpose_to_bf16<<<dim3(32, 32),  tb, 0, stream>>>(Wk, wtK, 1024, 1024);
  transpose_to_bf16<<<dim3(32, 32),  tb, 0, stream>>>(Wv, wtV, 1024, 1024);
  transpose_to_bf16<<<dim3(32, 32),  tb, 0, stream>>>(Wo, wtO, 1024, 1024);
  transpose_to_bf16<<<dim3(128, 32), tb, 0, stream>>>(W1, wtW1, 1024, 4096);
  transpose_to_bf16<<<dim3(32, 128), tb, 0, stream>>>(W2, wtW2, 4096, 1024);

  ln_kernel<<<MTOT, 256, 0, stream>>>(x, g1, s1, h);

  // fused QKV: Bt = [wtQ;wtK;wtV] (contiguous), N=3072
  gemm_gl<0, 128><<<dim3(24, 32), 256, 0, stream>>>(h, wtQ, MTOT, QKVN, 1024,
                                                    nullptr, nullptr, nullptr, qkv);

  transpose_v<<<dim3(64, 2, 32), tb, 0, stream>>>(qkv, Vt);

  attn_mfma<<<dim3(32, 32), 256, 0, stream>>>(qkv, Vt, ctxb);

  // x_attn = x + ctx@Wo + bo  (fp32, into d_out)
  gemm_gl<1, 64><<<dim3(16, 32), 256, 0, stream>>>(ctxb, wtO, MTOT, 1024, 1024,
                                                   bo, x, out, nullptr);

  ln_kernel<<<MTOT, 256, 0, stream>>>(out, g2, s2, h2);

  gemm_gl<2, 128><<<dim3(32, 32), 256, 0, stream>>>(h2, wtW1, MTOT, DFF, 1024,
                                                    b1, nullptr, nullptr, gbuf);

  // out = x_attn + gbuf@W2 + b2
  gemm_gl<3, 64><<<dim3(16, 32), 256, 0, stream>>>(gbuf, wtW2, MTOT, 1024, DFF,
                                                   b2, out, out, nullptr);
}

// Round 4
// 303.786 us; speedup vs baseline: 8.1073x; 1.1286x over previous
//
#include <hip/hip_runtime.h>
#include <hip/hip_bf16.h>

typedef __attribute__((ext_vector_type(8))) short short8;
typedef __attribute__((ext_vector_type(4))) float f32x4;

#define EMB   1024
#define DFF   4096
#define S_LEN 2048
#define NB    2
#define MTOT  (NB * S_LEN)   // 4096
#define HEADS 16
#define HDIM  64
#define QKVN  3072           // fused QKV output width
#define BK    32

__device__ __forceinline__ float bf2f(unsigned short u) {
  return __uint_as_float(((unsigned int)u) << 16);
}
__device__ __forceinline__ unsigned short f2bf(float f) {
  unsigned int x = __float_as_uint(f);
  unsigned int r = (x + 0x7fffu + ((x >> 16) & 1u)) >> 16;  // RN
  return (unsigned short)r;
}

// async global->LDS, 16B per lane; lptr must be wave-uniform (HW adds lane*16)
__device__ __forceinline__ void gl_lds16(const unsigned short* g, unsigned short* l) {
  __builtin_amdgcn_global_load_lds(
      (const __attribute__((address_space(1))) unsigned int*)g,
      (__attribute__((address_space(3))) unsigned int*)l, 16, 0, 0);
}

// ---------------------------------------------------------------------------
// Weight fp32 [K,N] -> bf16 [N,K]
// ---------------------------------------------------------------------------
__global__ __launch_bounds__(256) void transpose_to_bf16(
    const float* __restrict__ W, unsigned short* __restrict__ Wt, int K, int N)
{
  __shared__ float t[32][33];
  const int n0 = blockIdx.x * 32, k0 = blockIdx.y * 32;
  const int tx = threadIdx.x, ty = threadIdx.y;
#pragma unroll
  for (int i = 0; i < 4; ++i) {
    int r = ty + i * 8;
    t[r][tx] = W[(size_t)(k0 + r) * N + n0 + tx];
  }
  __syncthreads();
#pragma unroll
  for (int i = 0; i < 4; ++i) {
    int r = ty + i * 8;
    Wt[(size_t)(n0 + r) * K + k0 + tx] = f2bf(t[tx][r]);
  }
}

// ---------------------------------------------------------------------------
// V slice of fused qkv [token, 3072] -> Vt [(b,h), d, s]
// grid (S/32, HDIM/32, NB*HEADS), block (32,8)
// ---------------------------------------------------------------------------
__global__ __launch_bounds__(256) void transpose_v(
    const unsigned short* __restrict__ qkv, unsigned short* __restrict__ Vt)
{
  __shared__ unsigned short t[32][33];
  const int s0 = blockIdx.x * 32, d0 = blockIdx.y * 32, bh = blockIdx.z;
  const int b = bh >> 4, h = bh & 15;
  const int tx = threadIdx.x, ty = threadIdx.y;
#pragma unroll
  for (int i = 0; i < 4; ++i) {
    int r = ty + i * 8;  // s offset
    t[r][tx] = qkv[((size_t)(b * S_LEN + s0 + r)) * QKVN + 2048 + h * HDIM + d0 + tx];
  }
  __syncthreads();
#pragma unroll
  for (int i = 0; i < 4; ++i) {
    int r = ty + i * 8;  // d offset
    Vt[((size_t)bh * HDIM + d0 + r) * S_LEN + s0 + tx] = t[tx][r];
  }
}

// ---------------------------------------------------------------------------
// LayerNorm: fp32 [rows,1024] -> bf16 [rows,1024].  block 256, grid rows.
// ---------------------------------------------------------------------------
__global__ __launch_bounds__(256) void ln_kernel(
    const float* __restrict__ X, const float* __restrict__ g,
    const float* __restrict__ sh, unsigned short* __restrict__ H)
{
  const int row = blockIdx.x, t = threadIdx.x;
  const float* xr = X + (size_t)row * EMB;
  float4 v = *(const float4*)(xr + t * 4);
  float s  = v.x + v.y + v.z + v.w;
  float ss = v.x * v.x + v.y * v.y + v.z * v.z + v.w * v.w;
#pragma unroll
  for (int off = 32; off > 0; off >>= 1) {
    s  += __shfl_xor(s, off);
    ss += __shfl_xor(ss, off);
  }
  __shared__ float rs[4], rss[4];
  const int wid = t >> 6;
  if ((t & 63) == 0) { rs[wid] = s; rss[wid] = ss; }
  __syncthreads();
  s  = rs[0] + rs[1] + rs[2] + rs[3];
  ss = rss[0] + rss[1] + rss[2] + rss[3];
  const float mean = s * (1.f / EMB);
  const float var  = ss * (1.f / EMB) - mean * mean;
  const float rstd = rsqrtf(var + 1e-5f);
  float4 gv = *(const float4*)(g + t * 4);
  float4 sv = *(const float4*)(sh + t * 4);
  ushort4 o;
  o.x = f2bf((v.x - mean) * rstd * gv.x + sv.x);
  o.y = f2bf((v.y - mean) * rstd * gv.y + sv.y);
  o.z = f2bf((v.z - mean) * rstd * gv.z + sv.z);
  o.w = f2bf((v.w - mean) * rstd * gv.w + sv.w);
  *(ushort4*)(H + (size_t)row * EMB + t * 4) = o;
}

// ---------------------------------------------------------------------------
// GEMM  C[M,N] = A[M,K] * Bt[N,K]^T   (bf16, K-contiguous operands)
// BM=128, BN in {128,64}, BK=32, 4 waves, global_load_lds double-buffered.
// MODE 0: outb = acc * (c<1024 ? 0.125 : 1)   (fused QKV; Q pre-scaled)
// MODE 1: outf = acc + bias[c] + resf
// MODE 2: outb = gelu(acc + bias[c])
// MODE 3: outf = acc + bias[c] + resf   (in-place ok, same-thread idx)
// ---------------------------------------------------------------------------
__device__ __forceinline__ float gelu_tanh_f(float v) {
  float u = v + 0.044715f * v * v * v;
  float t = tanhf(0.7978845608028654f * u);
  return 0.5f * v * (1.0f + t);
}

template <int MODE, int BN>
__global__ __launch_bounds__(256, 2) void gemm_gl(
    const unsigned short* __restrict__ A, const unsigned short* __restrict__ Bt,
    int M, int N, int K,
    const float* __restrict__ bias, const float* __restrict__ resf,
    float* __restrict__ outf, unsigned short* __restrict__ outb)
{
  constexpr int NFRAG = BN / 32;         // col fragments per wave
  __shared__ unsigned short As[2][128 * BK];
  __shared__ unsigned short Bs[2][BN * BK];

  const int tid = threadIdx.x;
  const int lane = tid & 63, wid = tid >> 6;
  const int m0 = blockIdx.y * 128, n0 = blockIdx.x * BN;
  const int wr = wid >> 1, wc = wid & 1;
  const int l16 = lane & 15, kg = lane >> 4;

  const int sr = lane >> 2;
  const int sc = (lane & 3) * 8;

  const unsigned short* Abase = A + (size_t)m0 * K;
  const unsigned short* Bbase = Bt + (size_t)n0 * K;

  f32x4 acc[4][NFRAG];
#pragma unroll
  for (int i = 0; i < 4; ++i)
#pragma unroll
    for (int j = 0; j < NFRAG; ++j) acc[i][j] = (f32x4){0.f, 0.f, 0.f, 0.f};

  const int nt = K / BK;

#define STAGE(buf, t)                                                          \
  do {                                                                         \
    const int k0_ = (t) * BK;                                                  \
    _Pragma("unroll")                                                          \
    for (int i_ = 0; i_ < 2; ++i_) {                                           \
      const int chunk_ = wid * 2 + i_;                                         \
      gl_lds16(Abase + (size_t)(chunk_ * 16 + sr) * K + k0_ + sc,              \
               &As[buf][0] + chunk_ * 512);                                    \
    }                                                                          \
    _Pragma("unroll")                                                          \
    for (int i_ = 0; i_ < BN / 64; ++i_) {                                     \
      const int chunk_ = wid * (BN / 64) + i_;                                 \
      gl_lds16(Bbase + (size_t)(chunk_ * 16 + sr) * K + k0_ + sc,              \
               &Bs[buf][0] + chunk_ * 512);                                    \
    }                                                                          \
  } while (0)

  STAGE(0, 0);
  __syncthreads();
  int cur = 0;
  for (int t = 0; t < nt; ++t) {
    if (t + 1 < nt) STAGE(cur ^ 1, t + 1);
    short8 af[4], bfr[NFRAG];
#pragma unroll
    for (int i = 0; i < 4; ++i)
      af[i] = *(const short8*)(&As[cur][(wr * 64 + i * 16 + l16) * BK + kg * 8]);
#pragma unroll
    for (int j = 0; j < NFRAG; ++j)
      bfr[j] = *(const short8*)(&Bs[cur][(wc * (BN / 2) + j * 16 + l16) * BK + kg * 8]);
#pragma unroll
    for (int i = 0; i < 4; ++i)
#pragma unroll
      for (int j = 0; j < NFRAG; ++j)
        acc[i][j] = __builtin_amdgcn_mfma_f32_16x16x32_bf16(af[i], bfr[j], acc[i][j], 0, 0, 0);
    __syncthreads();
    cur ^= 1;
  }
#undef STAGE

#pragma unroll
  for (int i = 0; i < 4; ++i) {
#pragma unroll
    for (int j = 0; j < NFRAG; ++j) {
      const int c = n0 + wc * (BN / 2) + j * 16 + l16;
#pragma unroll
      for (int r = 0; r < 4; ++r) {
        const int row = m0 + wr * 64 + i * 16 + kg * 4 + r;
        const size_t idx = (size_t)row * N + c;
        float v = acc[i][j][r];
        if constexpr (MODE == 0) {
          outb[idx] = f2bf(c < 1024 ? v * 0.125f : v);  // pre-scale Q by 1/sqrt(D)
        } else if constexpr (MODE == 1) {
          outf[idx] = v + bias[c] + resf[idx];
        } else if constexpr (MODE == 2) {
          outb[idx] = f2bf(gelu_tanh_f(v + bias[c]));
        } else {
          outf[idx] = v + bias[c] + resf[idx];
        }
      }
    }
  }
}

// ---------------------------------------------------------------------------
// MFMA causal flash attention, swapped-operand form.
// Block = 4 waves = 64 q-rows of one (b,h).  grid (S/64, B*H), qtile reversed.
// S^T = mfma(Kfrag, Qfrag): lane holds S^T[key=j*16+kg*4+r][q=l16]
//   -> softmax row-reduce = in-lane tree + 2 shfl_xor (16,32); m/l scalar/lane.
// P stored [q][key] in LDS (b64 packed writes), read as PV B-fragment.
// O^T = mfma(Vfrag, Pfrag): lane holds O[q=l16][d=dt*16+kg*4+r].
// T14: next tile's global loads issue after barrier, before compute.
// ---------------------------------------------------------------------------
__global__ __launch_bounds__(256) void attn_mfma(
    const unsigned short* __restrict__ qkv, const unsigned short* __restrict__ Vt,
    unsigned short* __restrict__ ctx)
{
  __shared__ unsigned short Ks[64][72];
  __shared__ unsigned short Vs[64][72];   // [d][key]
  __shared__ unsigned short Ps[4][16][72];

  const int tid  = threadIdx.x;
  const int lane = tid & 63, wv = tid >> 6;
  const int l16  = lane & 15, kg = lane >> 4;
  const int qt   = (int)gridDim.x - 1 - (int)blockIdx.x;   // heavy tiles first
  const int q0   = qt * 64;
  const int bh   = blockIdx.y;
  const int b    = bh >> 4, h = bh & 15;

  const size_t qbase  = ((size_t)b * S_LEN) * QKVN + h * HDIM;
  const size_t kbase  = qbase + 1024;
  const size_t vtbase = ((size_t)bh * HDIM) * S_LEN;
  const size_t cbase  = ((size_t)b * S_LEN) * EMB + h * HDIM;

  short8 qf[2];
  {
    const unsigned short* qrow = qkv + qbase + (size_t)(q0 + wv * 16 + l16) * QKVN;
    qf[0] = *(const short8*)(qrow + kg * 8);
    qf[1] = *(const short8*)(qrow + 32 + kg * 8);
  }

  f32x4 o[4];
#pragma unroll
  for (int dt = 0; dt < 4; ++dt) o[dt] = (f32x4){0.f, 0.f, 0.f, 0.f};
  float m = -1e30f, l = 0.f;     // per-lane: q = l16 (replicated across kg)

  const int srow = tid >> 2;
  const int scol = (tid & 3) * 16;
  const int qloc = wv * 16 + l16;

  const int ntiles = qt + 1;

  // prologue: stage tile 0 into regs
  const unsigned short* ksrc = qkv + kbase + (size_t)srow * QKVN + scol;
  const unsigned short* vsrc = Vt + vtbase + (size_t)srow * S_LEN + scol;
  short8 k0 = *(const short8*)(ksrc);
  short8 k1 = *(const short8*)(ksrc + 8);
  short8 v0 = *(const short8*)(vsrc);
  short8 v1 = *(const short8*)(vsrc + 8);

  for (int kt = 0; kt < ntiles; ++kt) {
    __syncthreads();   // previous tile's LDS reads done
    *(short8*)(&Ks[srow][scol])     = k0;
    *(short8*)(&Ks[srow][scol + 8]) = k1;
    *(short8*)(&Vs[srow][scol])     = v0;
    *(short8*)(&Vs[srow][scol + 8]) = v1;
    __syncthreads();

    // T14: issue next tile's loads now; latency hides under compute below
    if (kt + 1 < ntiles) {
      const unsigned short* kn = qkv + kbase + (size_t)((kt + 1) * 64 + srow) * QKVN + scol;
      const unsigned short* vn = Vt + vtbase + (size_t)srow * S_LEN + (kt + 1) * 64 + scol;
      k0 = *(const short8*)(kn);
      k1 = *(const short8*)(kn + 8);
      v0 = *(const short8*)(vn);
      v1 = *(const short8*)(vn + 8);
    }

    // ---- S^T = K Q^T (per wave: 64 keys x 16 q) ----
    f32x4 sa[4];
#pragma unroll
    for (int j = 0; j < 4; ++j) {
      sa[j] = (f32x4){0.f, 0.f, 0.f, 0.f};
      short8 kf0 = *(const short8*)(&Ks[j * 16 + l16][kg * 8]);
      short8 kf1 = *(const short8*)(&Ks[j * 16 + l16][32 + kg * 8]);
      sa[j] = __builtin_amdgcn_mfma_f32_16x16x32_bf16(kf0, qf[0], sa[j], 0, 0, 0);
      sa[j] = __builtin_amdgcn_mfma_f32_16x16x32_bf16(kf1, qf[1], sa[j], 0, 0, 0);
    }
    // lane now holds S^T[key = j*16 + kg*4 + r][q = l16]

    // ---- causal mask (diag tile only) ----
    if (kt == qt) {
#pragma unroll
      for (int j = 0; j < 4; ++j)
#pragma unroll
        for (int r = 0; r < 4; ++r)
          if (j * 16 + kg * 4 + r > qloc) sa[j][r] = -1e30f;
    }

    // ---- online softmax, q = l16 per lane ----
    float m0j = fmaxf(fmaxf(sa[0][0], sa[0][1]), fmaxf(sa[0][2], sa[0][3]));
    float m1j = fmaxf(fmaxf(sa[1][0], sa[1][1]), fmaxf(sa[1][2], sa[1][3]));
    float m2j = fmaxf(fmaxf(sa[2][0], sa[2][1]), fmaxf(sa[2][2], sa[2][3]));
    float m3j = fmaxf(fmaxf(sa[3][0], sa[3][1]), fmaxf(sa[3][2], sa[3][3]));
    float mx = fmaxf(fmaxf(m0j, m1j), fmaxf(m2j, m3j));
    mx = fmaxf(mx, __shfl_xor(mx, 16));
    mx = fmaxf(mx, __shfl_xor(mx, 32));
    const float mn = fmaxf(m, mx);
    const float fac = __expf(m - mn);
    m = mn;
    float ps = 0.f;
#pragma unroll
    for (int j = 0; j < 4; ++j) {
      float p0 = __expf(sa[j][0] - mn);
      float p1 = __expf(sa[j][1] - mn);
      float p2 = __expf(sa[j][2] - mn);
      float p3 = __expf(sa[j][3] - mn);
      sa[j][0] = p0; sa[j][1] = p1; sa[j][2] = p2; sa[j][3] = p3;
      ps += (p0 + p1) + (p2 + p3);
    }
    ps += __shfl_xor(ps, 16);
    ps += __shfl_xor(ps, 32);
    l = l * fac + ps;

    // ---- write P[q=l16][key] as packed b64 ----
#pragma unroll
    for (int j = 0; j < 4; ++j) {
      ushort4 pw;
      pw.x = f2bf(sa[j][0]); pw.y = f2bf(sa[j][1]);
      pw.z = f2bf(sa[j][2]); pw.w = f2bf(sa[j][3]);
      *(ushort4*)(&Ps[wv][l16][j * 16 + kg * 4]) = pw;
    }

    // ---- rescale o ----
#pragma unroll
    for (int dt = 0; dt < 4; ++dt)
#pragma unroll
      for (int r = 0; r < 4; ++r) o[dt][r] *= fac;

    // ---- O^T += V^T P^T ----
    short8 pf0 = *(const short8*)(&Ps[wv][l16][kg * 8]);
    short8 pf1 = *(const short8*)(&Ps[wv][l16][32 + kg * 8]);
#pragma unroll
    for (int dt = 0; dt < 4; ++dt) {
      short8 vf0 = *(const short8*)(&Vs[dt * 16 + l16][kg * 8]);
      short8 vf1 = *(const short8*)(&Vs[dt * 16 + l16][32 + kg * 8]);
      o[dt] = __builtin_amdgcn_mfma_f32_16x16x32_bf16(vf0, pf0, o[dt], 0, 0, 0);
      o[dt] = __builtin_amdgcn_mfma_f32_16x16x32_bf16(vf1, pf1, o[dt], 0, 0, 0);
    }
  }

  // ---- ctx[q=l16][d] = o / l  (packed ushort4 per dt) ----
  const float inv = 1.0f / l;
  const int qrow = q0 + wv * 16 + l16;
#pragma unroll
  for (int dt = 0; dt < 4; ++dt) {
    ushort4 cw;
    cw.x = f2bf(o[dt][0] * inv); cw.y = f2bf(o[dt][1] * inv);
    cw.z = f2bf(o[dt][2] * inv); cw.w = f2bf(o[dt][3] * inv);
    *(ushort4*)(&ctx[cbase + (size_t)qrow * EMB + dt * 16 + kg * 4]) = cw;
  }
}

// ---------------------------------------------------------------------------
// ws layout (MB): 0-2 wtQ | 2-4 wtK | 4-6 wtV (contiguous 0-6 = fused QKV Bt)
//   6-8 wtO | 8-16 wtW1 | 16-24 wtW2
//   24-32 h (ln1) -> ctx (attn) -> h2 (ln2)
//   32-56 qkv [4096,3072] | 56-64 Vt | 32-64 gbuf (after attn)
// x_attn fp32 lives in d_out.  Peak ws: 64 MB.
// ---------------------------------------------------------------------------
extern "C" void kernel_launch(void* const* d_in, const int* in_sizes, int n_in,
                              void* d_out, int out_size, void* d_ws, size_t ws_size,
                              hipStream_t stream)
{
  const float* x  = (const float*)d_in[0];
  const float* Wq = (const float*)d_in[1];
  const float* Wk = (const float*)d_in[2];
  const float* Wv = (const float*)d_in[3];
  const float* Wo = (const float*)d_in[4];
  const float* bo = (const float*)d_in[5];
  const float* W1 = (const float*)d_in[6];
  const float* b1 = (const float*)d_in[7];
  const float* W2 = (const float*)d_in[8];
  const float* b2 = (const float*)d_in[9];
  const float* g1 = (const float*)d_in[10];
  const float* s1 = (const float*)d_in[11];
  const float* g2 = (const float*)d_in[12];
  const float* s2 = (const float*)d_in[13];

  float* out = (float*)d_out;
  char* ws = (char*)d_ws;
  const size_t MB = 1024 * 1024;
  unsigned short* wtQ  = (unsigned short*)(ws + 0 * MB);
  unsigned short* wtK  = (unsigned short*)(ws + 2 * MB);
  unsigned short* wtV  = (unsigned short*)(ws + 4 * MB);
  unsigned short* wtO  = (unsigned short*)(ws + 6 * MB);
  unsigned short* wtW1 = (unsigned short*)(ws + 8 * MB);
  unsigned short* wtW2 = (unsigned short*)(ws + 16 * MB);
  unsigned short* h    = (unsigned short*)(ws + 24 * MB);
  unsigned short* qkv  = (unsigned short*)(ws + 32 * MB);
  unsigned short* Vt   = (unsigned short*)(ws + 56 * MB);
  unsigned short* ctxb = h;
  unsigned short* h2   = h;
  unsigned short* gbuf = qkv;            // reuse 32..64MB after attn

  dim3 tb(32, 8);
  transpose_to_bf16<<<dim3(32, 32),  tb, 0, stream>>>(Wq, wtQ, 1024, 1024);
  transpose_to_bf16<<<dim3(32, 32),  tb, 0, stream>>>(Wk, wtK, 1024, 1024);
  transpose_to_bf16<<<dim3(32, 32),  tb, 0, stream>>>(Wv, wtV, 1024, 1024);
  transpose_to_bf16<<<dim3(32, 32),  tb, 0, stream>>>(Wo, wtO, 1024, 1024);
  transpose_to_bf16<<<dim3(128, 32), tb, 0, stream>>>(W1, wtW1, 1024, 4096);
  transpose_to_bf16<<<dim3(32, 128), tb, 0, stream>>>(W2, wtW2, 4096, 1024);

  ln_kernel<<<MTOT, 256, 0, stream>>>(x, g1, s1, h);

  // fused QKV (Q pre-scaled by 1/8 in epilogue): Bt = [wtQ;wtK;wtV], N=3072
  gemm_gl<0, 128><<<dim3(24, 32), 256, 0, stream>>>(h, wtQ, MTOT, QKVN, 1024,
                                                    nullptr, nullptr, nullptr, qkv);

  transpose_v<<<dim3(64, 2, 32), tb, 0, stream>>>(qkv, Vt);

  attn_mfma<<<dim3(32, 32), 256, 0, stream>>>(qkv, Vt, ctxb);

  // x_attn = x + ctx@Wo + bo  (fp32, into d_out)
  gemm_gl<1, 64><<<dim3(16, 32), 256, 0, stream>>>(ctxb, wtO, MTOT, 1024, 1024,
                                                   bo, x, out, nullptr);

  ln_kernel<<<MTOT, 256, 0, stream>>>(out, g2, s2, h2);

  gemm_gl<2, 128><<<dim3(32, 32), 256, 0, stream>>>(h2, wtW1, MTOT, DFF, 1024,
                                                    b1, nullptr, nullptr, gbuf);

  // out = x_attn + gbuf@W2 + b2
  gemm_gl<3, 64><<<dim3(16, 32), 256, 0, stream>>>(gbuf, wtW2, MTOT, 1024, DFF,
                                                   b2, out, out, nullptr);
}